// Round 8
// baseline (813.573 us; speedup 1.0000x reference)
//
#include <hip/hip_runtime.h>
#include <hip/hip_bf16.h>

// LSTM encoder, single fused kernel (producer/consumer).
//   Grid = 256 WGs x 256 thr. WGs 0-63: persistent recurrence, one batch row
//   each. WGs 64-255: xg producers, 8 timesteps per chunk (256 chunks),
//   publishing via agent-scope release flags in d_ws.
// Consumer (R8 = R7 K-split dots + R4 pair-split tail):
//   R7 post-mortem: consumer-CU VALUBusy ~60% (16.2% GPU-wide x 256/64) ->
//   step is substantially ISSUE-bound; R7's tail ran 5 transcendental chains
//   per lane (tanh g, sig o, sig i, sig f, tanh c). R8 splits the tail
//   across the K-pair (merges already give both lanes full sums):
//     kh0: tanh(g) [hidden under block2 dots], sig(i), A=si*tg
//     kh1: sig(o)+so127 [hidden], sig(f)
//   one DPP swap (A <-> sf), both lanes form c, one tanh(c); kh1 (holds so)
//   quantizes h and writes LDS + out. 3 chains/lane, 2 converts/lane.
//   Dot layout unchanged from R7: K-split pair (kh = l&1), 4 gates x 16
//   sdot4 on own K-half, exact i32 K-merge via DPP quad_perm per gate,
//   4x ds_read_b128/lane after the barrier.
//   Scaffold identical to R4/R7: streaming in-place xg prefetch (substep s
//   loads next-chunk slot s-1; slot 7 reloaded at s==7), fence-free hot-loop
//   flag spin (every xg line first-touched strictly after its flag is
//   observed two chunks ahead; lines not shared across consumers; chunk-0
//   dummy re-reads immutable after flag 0), startup acquire fences,
//   s_setprio(1), one lgkm-only barrier/step, h ping-pong = 256 B LDS.
// Fallback single kernel if ws_size too small.

namespace {

constexpr int T_LEN  = 2048;
constexpr int Bsz    = 64;
constexpr int Dd     = 128;
constexpr int Hh     = 128;
constexpr int Gg     = 512;
constexpr int XS     = 136;    // bf16 LDS row stride (producer A-tile / fallback)
constexpr int NCHUNK = 256;    // 8 timesteps per chunk
constexpr int CONS   = 64;     // consumer WGs (one per batch row)
constexpr int PROD   = 192;    // producer WGs
constexpr unsigned int SENT = 0x5EC7C0DEu;

typedef __attribute__((ext_vector_type(8))) short   short8;
typedef __attribute__((ext_vector_type(4))) float   floatx4;
typedef __attribute__((ext_vector_type(4))) int     intx4;
typedef __attribute__((ext_vector_type(2))) unsigned int uintx2;

#define MFMA16(a, b, c) __builtin_amdgcn_mfma_f32_16x16x32_bf16((a), (b), (c), 0, 0, 0)

#if __has_builtin(__builtin_amdgcn_sdot4)
__device__ __forceinline__ int dot4i8(int a, int b, int c) {
    return __builtin_amdgcn_sdot4(a, b, c, false);
}
#else
__device__ __forceinline__ int dot4i8(int a, int b, int c) {
#pragma unroll
    for (int j = 0; j < 4; ++j)
        c += ((a << (24 - 8 * j)) >> 24) * ((b << (24 - 8 * j)) >> 24);
    return c;
}
#endif

// value from partner lane^1 (quad_perm [1,0,3,2]) -- full-rate VALU
__device__ __forceinline__ int xor1_i(int v) {
    return __builtin_amdgcn_mov_dpp(v, 0xB1, 0xF, 0xF, true);
}

__device__ __forceinline__ float sigmoidf_(float x) {
    return __builtin_amdgcn_rcpf(1.0f + __builtin_amdgcn_exp2f(x * -1.44269504f));
}
__device__ __forceinline__ float tanhf_(float x) {
    return __builtin_fmaf(-2.0f,
        __builtin_amdgcn_rcpf(1.0f + __builtin_amdgcn_exp2f(x * 2.88539008f)), 1.0f);
}
__device__ __forceinline__ unsigned short f2bf(float f) {
    __hip_bfloat16 h = __float2bfloat16(f);  // RNE
    union { __hip_bfloat16 b; unsigned short u; } v; v.b = h; return v.u;
}
__device__ __forceinline__ float fi_(unsigned int u) {
    union { unsigned int u; float f; } v; v.u = u; return v.f;
}
__device__ __forceinline__ int f_as_i(float f) {
    union { float f; int i; } v; v.f = f; return v.i;
}
__device__ __forceinline__ float i_as_f(int i) {
    union { int i; float f; } v; v.i = i; return v.f;
}
__device__ __forceinline__ uintx2 f4bf(const float4 v) {
    union { unsigned short us[4]; uintx2 u2; } p;
    p.us[0] = f2bf(v.x); p.us[1] = f2bf(v.y); p.us[2] = f2bf(v.z); p.us[3] = f2bf(v.w);
    return p.u2;
}
__device__ __forceinline__ short8 ld8bf(const float* p) {
    const float4 a = *reinterpret_cast<const float4*>(p);
    const float4 b = *reinterpret_cast<const float4*>(p + 4);
    short8 s;
    s[0] = (short)f2bf(a.x); s[1] = (short)f2bf(a.y);
    s[2] = (short)f2bf(a.z); s[3] = (short)f2bf(a.w);
    s[4] = (short)f2bf(b.x); s[5] = (short)f2bf(b.y);
    s[6] = (short)f2bf(b.z); s[7] = (short)f2bf(b.w);
    return s;
}
// barrier without the compiler's vmcnt(0) drain: LDS-visibility only
__device__ __forceinline__ void lds_barrier() {
    asm volatile("s_waitcnt lgkmcnt(0)\n\ts_barrier" ::: "memory");
}
// startup-path wait: spin + full acquire fence
__device__ __forceinline__ void wait_chunk(const unsigned int* flags, int k) {
    while (__hip_atomic_load(&flags[k], __ATOMIC_RELAXED,
                             __HIP_MEMORY_SCOPE_AGENT) != SENT)
        __builtin_amdgcn_s_sleep(2);
    __builtin_amdgcn_fence(__ATOMIC_ACQUIRE, "agent");
}
// hot-loop wait: spin only, NO fence (see header comment for the argument)
__device__ __forceinline__ void spin_chunk(const unsigned int* flags, int k) {
    while (__hip_atomic_load(&flags[k], __ATOMIC_RELAXED,
                             __HIP_MEMORY_SCOPE_AGENT) != SENT)
        __builtin_amdgcn_s_sleep(2);
}

// =================== fused producer/consumer kernel ==========================
__global__ __launch_bounds__(256) void lstm_fused_all(
    const int*   __restrict__ tokens,
    const float* __restrict__ emb,
    const float* __restrict__ Wih,
    const float* __restrict__ Whh,
    const float* __restrict__ bih,
    const float* __restrict__ bhh,
    unsigned short* __restrict__ xg,     // [T][64][128][4] bf16, in d_ws
    unsigned int*   __restrict__ flags,  // [NCHUNK], in d_ws after xg
    float*       __restrict__ out)       // [2][64][128] fp32
{
    __shared__ __align__(16) unsigned short albs[2][64 * XS];  // producer A-tile

    const int tid = threadIdx.x;

    if (blockIdx.x < CONS) {
        // ================= CONSUMER: one batch row ===========================
        __builtin_amdgcn_s_setprio(1);   // beat co-resident producers
        signed char (*hbuf)[128] =
            reinterpret_cast<signed char (*)[128]>(&albs[0][0]);  // [2][128]

        const int wv = tid >> 6;          // wave 0..3
        const int l  = tid & 63;
        const int kh = l & 1;             // K-half: 0 -> k<64, 1 -> k>=64
        const int c  = wv * 32 + (l >> 1);  // hidden column
        const int b  = blockIdx.x;        // batch row

        // pair-split tail constants:
        //   kh0 owns gates {i, g}: tanh(g) via 2*sig(2x)-1, then sig(i)
        //   kh1 owns gates {f, o}: sig(o), then sig(f)
        const float kf = kh ? 1.0f : 2.0f;    // block1 input & output scale
        const float kb = kh ? 0.0f : -1.0f;   // block1 output offset
        const int   sh = kh ? 0 : 16;         // bf16 unpack shift for xg

        // Whh rows {g*128+c} -> i8; full-row scale, quantize own K-half
        int   wq[4][16];
        float dq[4];
#pragma unroll
        for (int g = 0; g < 4; ++g) {
            const float* wr = Whh + (size_t)(g * 128 + c) * Hh;
            float am = 0.f;
#pragma unroll 8
            for (int k = 0; k < 128; k += 4) {
                const float4 v = *reinterpret_cast<const float4*>(wr + k);
                am = fmaxf(am, fmaxf(fmaxf(fabsf(v.x), fabsf(v.y)),
                                     fmaxf(fabsf(v.z), fabsf(v.w))));
            }
            const float swm = fmaxf(am, 1e-20f);
            dq[g] = swm * (1.0f / (127.0f * 127.0f));
            const float inv = 127.0f / swm;
#pragma unroll
            for (int d = 0; d < 16; ++d) {
                const float4 v =
                    *reinterpret_cast<const float4*>(wr + kh * 64 + d * 4);
                const int b0 = (int)__builtin_rintf(v.x * inv);
                const int b1 = (int)__builtin_rintf(v.y * inv);
                const int b2 = (int)__builtin_rintf(v.z * inv);
                const int b3 = (int)__builtin_rintf(v.w * inv);
                wq[g][d] = (b0 & 0xff) | ((b1 & 0xff) << 8) |
                           ((b2 & 0xff) << 16) | ((b3 & 0xff) << 24);
            }
        }
        // per-lane gate scales: block2 gate = kh (i/f), block1 gate = 2+kh (g/o)
        const float dqA = dq[kh];
        const float dqB = dq[2 + kh];

        // h(0) = 0 in regs (buffers always written before read); own K-half
        intx4 hv[4];
#pragma unroll
        for (int j = 0; j < 4; ++j) hv[j] = (intx4){0, 0, 0, 0};

        const unsigned short* xptr = xg + (size_t)b * Gg + c * 4;
        const size_t xstride = (size_t)Bsz * Gg;

        // startup: verify chunks 0 and 1 (full acquire); load chunk 0
        wait_chunk(flags, 0);
        uintx2 xc[8];
#pragma unroll
        for (int u = 0; u < 8; ++u)
            xc[u] = *reinterpret_cast<const uintx2*>(xptr + (size_t)u * xstride);
        wait_chunk(flags, 1);

        float c_state = 0.0f;
        float h_last  = 0.0f;
        unsigned int fpre = SENT;

        for (int g = 0; g < NCHUNK; ++g) {
            int tn = g + 1;
            if (tn >= NCHUNK) tn = 0;            // dummy re-read of chunk 0
            const size_t tb = (size_t)tn * 8;
#pragma unroll
            for (int s = 0; s < 8; ++s) {
                const uintx2 xv = xc[s];          // consume slot s FIRST

                // streaming in-place prefetch of chunk g+1:
                //   substep s>=1 loads slot s-1; substep 7 also re-loads
                //   slot 7 (just consumed above). ~7-substep use distance.
                if (s >= 1)
                    xc[s - 1] = *reinterpret_cast<const uintx2*>(
                        xptr + (tb + (s - 1)) * xstride);
                if (s == 7)
                    xc[7] = *reinterpret_cast<const uintx2*>(
                        xptr + (tb + 7) * xstride);

                if (s == 2) {
                    // prefetch the distance-2 flag (hide L2 latency)
                    if (g + 2 < NCHUNK)
                        fpre = __hip_atomic_load(&flags[g + 2], __ATOMIC_RELAXED,
                                                 __HIP_MEMORY_SCOPE_AGENT);
                }
                if (s == 4) {
                    // distance-2 flag check; fence-free (see header)
                    if (g + 2 < NCHUNK && fpre != SENT) spin_chunk(flags, g + 2);
                }

                // ---- block 1: gates {2,3} = {g,o}, own K-half ----
                // 4 chains, 8-deep each (2 chains/gate)
                int a0 = 0, a1 = 0, b0 = 0, b1 = 0;
#pragma unroll
                for (int j = 0; j < 4; ++j) {
                    const intx4 h4 = hv[j];
                    a0 = dot4i8(wq[2][j * 4 + 0], h4[0], a0);
                    a1 = dot4i8(wq[2][j * 4 + 1], h4[1], a1);
                    b0 = dot4i8(wq[3][j * 4 + 0], h4[0], b0);
                    b1 = dot4i8(wq[3][j * 4 + 1], h4[1], b1);
                    a0 = dot4i8(wq[2][j * 4 + 2], h4[2], a0);
                    a1 = dot4i8(wq[2][j * 4 + 3], h4[3], a1);
                    b0 = dot4i8(wq[3][j * 4 + 2], h4[2], b0);
                    b1 = dot4i8(wq[3][j * 4 + 3], h4[3], b1);
                }
                const int p2 = a0 + a1;            // partial sums, own K-half
                const int p3 = b0 + b1;
                // exact i32 K-merge with partner lane^1 (DPP)
                const int m2 = p2 + xor1_i(p2);
                const int m3 = p3 + xor1_i(p3);

                // block1 tail, pair-split (hidden under block 2 dot issue):
                //   kh0: tg = tanh(gv) = 2*sig(2gv)-1 ; kh1: so = sig(ov)
                const int   mB = kh ? m3 : m2;
                const float xB = fi_((xv.y << sh) & 0xffff0000u);  // g or o
                const float gB = (float)mB * dqB + xB;
                const float r2 = sigmoidf_(gB * kf);
                const float v2 = __builtin_fmaf(r2, kf, kb);  // tg / so
                const float so127 = v2 * 127.0f;              // kh1: so*127

                // ---- block 2: gates {0,1} = {i,f}, own K-half ----
                int c0 = 0, c1 = 0, d0 = 0, d1 = 0;
#pragma unroll
                for (int j = 0; j < 4; ++j) {
                    const intx4 h4 = hv[j];
                    c0 = dot4i8(wq[0][j * 4 + 0], h4[0], c0);
                    c1 = dot4i8(wq[0][j * 4 + 1], h4[1], c1);
                    d0 = dot4i8(wq[1][j * 4 + 0], h4[0], d0);
                    d1 = dot4i8(wq[1][j * 4 + 1], h4[1], d1);
                    c0 = dot4i8(wq[0][j * 4 + 2], h4[2], c0);
                    c1 = dot4i8(wq[0][j * 4 + 3], h4[3], c1);
                    d0 = dot4i8(wq[1][j * 4 + 2], h4[2], d0);
                    d1 = dot4i8(wq[1][j * 4 + 3], h4[3], d1);
                }
                const int p0 = c0 + c1;
                const int p1 = d0 + d1;
                const int m0 = p0 + xor1_i(p0);
                const int m1 = p1 + xor1_i(p1);

                // block2 tail, pair-split: kh0: si = sig(iv), A = si*tg;
                // kh1: sf = sig(fv). One DPP swap (A <-> sf), shared c update.
                const int   mA = kh ? m1 : m0;
                const float xA = fi_((xv.x << sh) & 0xffff0000u);  // i or f
                const float gA = (float)mA * dqA + xA;
                const float r1 = sigmoidf_(gA);       // si (kh0) / sf (kh1)
                const float Aa = r1 * v2;             // si*tg (kh0) / junk
                const float swv = i_as_f(xor1_i(f_as_i(kh ? r1 : Aa)));
                const float F   = kh ? r1 : swv;      // sf on both lanes
                const float Ag  = kh ? swv : Aa;      // si*tg on both lanes
                c_state = __builtin_fmaf(F, c_state, Ag);
                const float t2 = tanhf_(c_state);
                h_last = v2 * t2;                     // valid on kh1: so*t2

                const int nxt = (s & 1) ^ 1;        // buffer parity of t+1
                if (kh == 1) {
                    // fused quant: round(so*127 * t2) via magic-add FMA (RNE)
                    const int q =
                        f_as_i(__builtin_fmaf(so127, t2, 12582912.0f));
                    hbuf[nxt][c] = (signed char)(q & 0xff);
                }
                lds_barrier();  // lgkm-only: h visible, vmem stays in flight
                // own K-half only: 4 x ds_read_b128 (half the LDS requests)
#pragma unroll
                for (int j = 0; j < 4; ++j)
                    hv[j] = *reinterpret_cast<const intx4*>(
                        &hbuf[nxt][kh * 64 + j * 16]);
            }
        }

        if (kh == 1) {
            out[b * Hh + c]            = h_last;
            out[Bsz * Hh + b * Hh + c] = c_state;
        }
    } else {
        // ================= PRODUCER: xg chunks of 8 timesteps ================
        const int pid  = blockIdx.x - CONS;
        const int wv   = tid >> 6;
        const int l    = tid & 63;
        const int quad = l >> 4;
        const int cl   = l & 15;
        const int srow = tid >> 2, sseg = tid & 3;   // staging: row, 32-col seg

        // bias for this lane's two hh columns (j = wv*2 + jj)
        float bias[2][4];
#pragma unroll
        for (int jj = 0; jj < 2; ++jj) {
            const int hhj = (wv * 2 + jj) * 16 + cl;
#pragma unroll
            for (int g = 0; g < 4; ++g)
                bias[jj][g] = bih[g * 128 + hhj] + bhh[g * 128 + hhj];
        }

        for (int chunk = pid; chunk < NCHUNK; chunk += PROD) {
            const int t0 = chunk * 8;

            {   // stage t0 into buf 0
                const int tok = tokens[srow * T_LEN + t0];
                const float* src = emb + (size_t)tok * Dd + sseg * 32;
#pragma unroll
                for (int p = 0; p < 4; ++p)
                    *reinterpret_cast<short8*>(
                        &albs[0][srow * XS + sseg * 32 + p * 8]) = ld8bf(src + p * 8);
            }
            __syncthreads();

            for (int tt = 0; tt < 8; ++tt) {
                const int cur = tt & 1, nxt = cur ^ 1;
                if (tt < 7) {   // stage next t
                    const int tok = tokens[srow * T_LEN + t0 + tt + 1];
                    const float* src = emb + (size_t)tok * Dd + sseg * 32;
#pragma unroll
                    for (int p = 0; p < 4; ++p)
                        *reinterpret_cast<short8*>(
                            &albs[nxt][srow * XS + sseg * 32 + p * 8]) =
                            ld8bf(src + p * 8);
                }

                // A-fragments for all 4 m-tiles x 4 k-chunks
                short8 af[4][4];
#pragma unroll
                for (int m = 0; m < 4; ++m)
#pragma unroll
                    for (int k = 0; k < 4; ++k)
                        af[m][k] = *reinterpret_cast<const short8*>(
                            &albs[cur][(m * 16 + cl) * XS + k * 32 + quad * 8]);

                const int t = t0 + tt;
#pragma unroll
                for (int jj = 0; jj < 2; ++jj) {
                    const int hhj = (wv * 2 + jj) * 16 + cl;
                    floatx4 acc[4][4];  // [g][m]
#pragma unroll
                    for (int g = 0; g < 4; ++g)
#pragma unroll
                        for (int m = 0; m < 4; ++m)
                            acc[g][m] = (floatx4){0.f, 0.f, 0.f, 0.f};
#pragma unroll
                    for (int g = 0; g < 4; ++g) {
                        const int n = g * 128 + hhj;
                        short8 bf[4];
#pragma unroll
                        for (int k = 0; k < 4; ++k)
                            bf[k] = ld8bf(Wih + (size_t)n * Dd + k * 32 + quad * 8);
#pragma unroll
                        for (int k = 0; k < 4; ++k)
#pragma unroll
                            for (int m = 0; m < 4; ++m)
                                acc[g][m] = MFMA16(af[m][k], bf[k], acc[g][m]);
                    }
                    // pack 4 gates per (b-row) and store 8 B
#pragma unroll
                    for (int m = 0; m < 4; ++m) {
#pragma unroll
                        for (int r = 0; r < 4; ++r) {
                            const int brow = m * 16 + quad * 4 + r;
                            union { unsigned short us[4]; uintx2 u2; } p;
#pragma unroll
                            for (int g = 0; g < 4; ++g)
                                p.us[g] = f2bf(acc[g][m][r] + bias[jj][g]);
                            *reinterpret_cast<uintx2*>(
                                xg + ((size_t)t * Bsz + brow) * Gg + hhj * 4) =
                                p.u2;
                        }
                    }
                }
                __syncthreads();  // staged buf visible; stores drained (vmcnt0)
            }

            // release: all 256 threads' stores are complete (barrier drained)
            if (tid == 0) {
                __builtin_amdgcn_fence(__ATOMIC_RELEASE, "agent");
                __hip_atomic_store(&flags[chunk], SENT, __ATOMIC_RELAXED,
                                   __HIP_MEMORY_SCOPE_AGENT);
            }
        }
    }
}

// ---------------- Fallback (R2 working kernel) if ws too small ---------------
__global__ __launch_bounds__(512, 2) void lstm_fused_fb(
    const int*   __restrict__ tokens,
    const float* __restrict__ emb,
    const float* __restrict__ Wih,
    const float* __restrict__ Whh,
    const float* __restrict__ bih,
    const float* __restrict__ bhh,
    float*       __restrict__ out)
{
    __shared__ unsigned short xbuf[2][16 * XS];
    __shared__ unsigned short hbuf2[2][16 * XS];
    __shared__ float scratch[4 * Gg];

    const int tid  = threadIdx.x;
    const int w    = tid >> 6;
    const int l    = tid & 63;
    const int quad = l >> 4;
    const int cl   = l & 15;
    const int bbase = blockIdx.x * 4;
    const int rr = tid >> 7;
    const int hh = tid & 127;

    short8 wih[4][4], whh[4][4];
    float  bias[4];
#pragma unroll
    for (int q = 0; q < 4; ++q) {
        const int n = q * 128 + w * 16 + cl;
#pragma unroll
        for (int kk = 0; kk < 4; ++kk) {
            const int k0 = kk * 32 + quad * 8;
            wih[q][kk] = ld8bf(Wih + n * Dd + k0);
            whh[q][kk] = ld8bf(Whh + n * Hh + k0);
        }
        bias[q] = bih[n] + bhh[n];
    }

    for (int i = tid; i < 16 * XS; i += 512) {
        xbuf[0][i] = 0; xbuf[1][i] = 0; hbuf2[0][i] = 0; hbuf2[1][i] = 0;
    }

    const bool gact = (tid < 128);
    const int  gr = tid >> 5;
    const int  gp = tid & 31;
    float4 gdataf = {0.f, 0.f, 0.f, 0.f};
    if (gact) {
        const int tok = tokens[(bbase + gr) * T_LEN + 0];
        gdataf = *reinterpret_cast<const float4*>(emb + (size_t)tok * Dd + gp * 4);
    }
    __syncthreads();
    if (gact) *reinterpret_cast<uintx2*>(&xbuf[0][gr * XS + gp * 4]) = f4bf(gdataf);
    if (gact) {
        const int tok = tokens[(bbase + gr) * T_LEN + 1];
        gdataf = *reinterpret_cast<const float4*>(emb + (size_t)tok * Dd + gp * 4);
    }
    __syncthreads();

    const int afrag_el = cl * XS + quad * 8;

    floatx4 acc[4];
#pragma unroll
    for (int q = 0; q < 4; ++q) acc[q] = (floatx4){bias[q], bias[q], bias[q], bias[q]};
    {
        short8 xf[4];
#pragma unroll
        for (int kk = 0; kk < 4; ++kk)
            xf[kk] = *reinterpret_cast<const short8*>(&xbuf[0][afrag_el + kk * 32]);
#pragma unroll
        for (int kk = 0; kk < 4; ++kk)
#pragma unroll
            for (int q = 0; q < 4; ++q)
                acc[q] = MFMA16(xf[kk], wih[q][kk], acc[q]);
    }

    float c_state = 0.0f, h_last = 0.0f;

    for (int t = 0; t < T_LEN; ++t) {
        const int cur = t & 1, nxt = cur ^ 1;
        short8 hf[4];
#pragma unroll
        for (int kk = 0; kk < 4; ++kk)
            hf[kk] = *reinterpret_cast<const short8*>(&hbuf2[cur][afrag_el + kk * 32]);
        if (gact && (t + 1 < T_LEN))
            *reinterpret_cast<uintx2*>(&xbuf[nxt][gr * XS + gp * 4]) = f4bf(gdataf);
        if (gact && (t + 2 < T_LEN)) {
            const int tok = tokens[(bbase + gr) * T_LEN + (t + 2)];
            gdataf = *reinterpret_cast<const float4*>(emb + (size_t)tok * Dd + gp * 4);
        }
#pragma unroll
        for (int kk = 0; kk < 4; ++kk)
#pragma unroll
            for (int q = 0; q < 4; ++q)
                acc[q] = MFMA16(hf[kk], whh[q][kk], acc[q]);
        if (quad == 0) {
#pragma unroll
            for (int q = 0; q < 4; ++q) {
                const int n = q * 128 + w * 16 + cl;
#pragma unroll
                for (int r = 0; r < 4; ++r)
                    scratch[r * Gg + n] = acc[q][r];
            }
        }
        __syncthreads();
#pragma unroll
        for (int q = 0; q < 4; ++q) acc[q] = (floatx4){bias[q], bias[q], bias[q], bias[q]};
        if (t + 1 < T_LEN) {
            short8 xf[4];
#pragma unroll
            for (int kk = 0; kk < 4; ++kk)
                xf[kk] = *reinterpret_cast<const short8*>(&xbuf[nxt][afrag_el + kk * 32]);
#pragma unroll
            for (int kk = 0; kk < 4; ++kk)
#pragma unroll
                for (int q = 0; q < 4; ++q)
                    acc[q] = MFMA16(xf[kk], wih[q][kk], acc[q]);
        }
        {
            const float iv = scratch[rr * Gg + hh];
            const float fv = scratch[rr * Gg + 128 + hh];
            const float gv = scratch[rr * Gg + 256 + hh];
            const float ov = scratch[rr * Gg + 384 + hh];
            const float si = sigmoidf_(iv);
            const float sf = sigmoidf_(fv);
            const float so = sigmoidf_(ov);
            const float tg = tanhf_(gv);
            c_state = sf * c_state + si * tg;
            h_last  = so * tanhf_(c_state);
            hbuf2[nxt][rr * XS + hh] = f2bf(h_last);
        }
        __syncthreads();
    }

    const int ob = (bbase + rr) * Hh + hh;
    out[ob]            = h_last;
    out[Bsz * Hh + ob] = c_state;
}

}  // namespace

extern "C" void kernel_launch(void* const* d_in, const int* in_sizes, int n_in,
                              void* d_out, int out_size, void* d_ws, size_t ws_size,
                              hipStream_t stream) {
    (void)in_sizes; (void)n_in; (void)out_size;
    const int*   tokens = (const int*)d_in[0];
    const float* emb    = (const float*)d_in[1];
    const float* Wih    = (const float*)d_in[2];
    const float* Whh    = (const float*)d_in[3];
    const float* bih    = (const float*)d_in[4];
    const float* bhh    = (const float*)d_in[5];

    const size_t xg_bytes = (size_t)T_LEN * Bsz * Gg * sizeof(unsigned short);  // 134 MB
    const size_t need = xg_bytes + NCHUNK * sizeof(unsigned int);
    if (ws_size >= need) {
        unsigned short* xg    = (unsigned short*)d_ws;
        unsigned int*   flags = (unsigned int*)((char*)d_ws + xg_bytes);
        lstm_fused_all<<<CONS + PROD, 256, 0, stream>>>(
            tokens, emb, Wih, Whh, bih, bhh, xg, flags, (float*)d_out);
    } else {
        lstm_fused_fb<<<16, 512, 0, stream>>>(tokens, emb, Wih, Whh, bih, bhh,
                                              (float*)d_out);
    }
}

// Round 9
// 799.264 us; speedup vs baseline: 1.0179x; 1.0179x over previous
//
#include <hip/hip_runtime.h>
#include <hip/hip_bf16.h>

// LSTM encoder, single fused kernel (producer/consumer).
//   Grid = 256 WGs x 256 thr. WGs 0-63: persistent recurrence, one batch row
//   each. WGs 64-255: xg producers, 8 timesteps per chunk (256 chunks),
//   publishing via agent-scope release flags in d_ws.
// Consumer (R9 = R7 exact + zero-init fold):
//   R8 post-mortem: pair-splitting the tail coupled the two lanes' chains
//   through a DPP swap on the c-update path (+42 cyc/step); redundant-but-
//   parallel per-lane tails win on a latency spine. R9 reverts to the R7
//   tail and only folds the 8 accumulator zero-inits into the first sdot4
//   of each chain (literal 0 as C operand -> -8 v_mov/step).
//   Layout: K-split lane pair (kh = l&1), 4 gates x 16 sdot4 on own K-half
//   (two blocks of 4 chains, 8-deep), exact i32 K-merge via one DPP
//   quad_perm add per gate, 4x ds_read_b128/lane after the barrier.
//   Tail: block1 {g,o}: tanh(g), sig(o) hidden under block2 dots; block2
//   {i,f}: sig(i) || sig(f) parallel -> c=fma(sf,c,si*tg) -> tanh(c) ->
//   magic-quant fma(so127, t2, 1.5*2^23) -> h write (kh==0 lanes).
//   Scaffold (R4): streaming in-place xg prefetch (substep s loads
//   next-chunk slot s-1; slot 7 reloaded at s==7), fence-free hot-loop flag
//   spin (every xg line first-touched strictly after its flag is observed
//   two chunks ahead; lines not shared across consumers; chunk-0 dummy
//   re-reads immutable after flag 0), startup acquire fences, s_setprio(1),
//   one lgkm-only barrier/step, h ping-pong = 256 B LDS.
// Fallback single kernel if ws_size too small.

namespace {

constexpr int T_LEN  = 2048;
constexpr int Bsz    = 64;
constexpr int Dd     = 128;
constexpr int Hh     = 128;
constexpr int Gg     = 512;
constexpr int XS     = 136;    // bf16 LDS row stride (producer A-tile / fallback)
constexpr int NCHUNK = 256;    // 8 timesteps per chunk
constexpr int CONS   = 64;     // consumer WGs (one per batch row)
constexpr int PROD   = 192;    // producer WGs
constexpr unsigned int SENT = 0x5EC7C0DEu;

typedef __attribute__((ext_vector_type(8))) short   short8;
typedef __attribute__((ext_vector_type(4))) float   floatx4;
typedef __attribute__((ext_vector_type(4))) int     intx4;
typedef __attribute__((ext_vector_type(2))) unsigned int uintx2;

#define MFMA16(a, b, c) __builtin_amdgcn_mfma_f32_16x16x32_bf16((a), (b), (c), 0, 0, 0)

#if __has_builtin(__builtin_amdgcn_sdot4)
__device__ __forceinline__ int dot4i8(int a, int b, int c) {
    return __builtin_amdgcn_sdot4(a, b, c, false);
}
#else
__device__ __forceinline__ int dot4i8(int a, int b, int c) {
#pragma unroll
    for (int j = 0; j < 4; ++j)
        c += ((a << (24 - 8 * j)) >> 24) * ((b << (24 - 8 * j)) >> 24);
    return c;
}
#endif

// value from partner lane^1 (quad_perm [1,0,3,2]) -- full-rate VALU
__device__ __forceinline__ int xor1_i(int v) {
    return __builtin_amdgcn_mov_dpp(v, 0xB1, 0xF, 0xF, true);
}

__device__ __forceinline__ float sigmoidf_(float x) {
    return __builtin_amdgcn_rcpf(1.0f + __builtin_amdgcn_exp2f(x * -1.44269504f));
}
__device__ __forceinline__ float tanhf_(float x) {
    return __builtin_fmaf(-2.0f,
        __builtin_amdgcn_rcpf(1.0f + __builtin_amdgcn_exp2f(x * 2.88539008f)), 1.0f);
}
__device__ __forceinline__ unsigned short f2bf(float f) {
    __hip_bfloat16 h = __float2bfloat16(f);  // RNE
    union { __hip_bfloat16 b; unsigned short u; } v; v.b = h; return v.u;
}
__device__ __forceinline__ float fi_(unsigned int u) {
    union { unsigned int u; float f; } v; v.u = u; return v.f;
}
__device__ __forceinline__ int f_as_i(float f) {
    union { float f; int i; } v; v.f = f; return v.i;
}
__device__ __forceinline__ uintx2 f4bf(const float4 v) {
    union { unsigned short us[4]; uintx2 u2; } p;
    p.us[0] = f2bf(v.x); p.us[1] = f2bf(v.y); p.us[2] = f2bf(v.z); p.us[3] = f2bf(v.w);
    return p.u2;
}
__device__ __forceinline__ short8 ld8bf(const float* p) {
    const float4 a = *reinterpret_cast<const float4*>(p);
    const float4 b = *reinterpret_cast<const float4*>(p + 4);
    short8 s;
    s[0] = (short)f2bf(a.x); s[1] = (short)f2bf(a.y);
    s[2] = (short)f2bf(a.z); s[3] = (short)f2bf(a.w);
    s[4] = (short)f2bf(b.x); s[5] = (short)f2bf(b.y);
    s[6] = (short)f2bf(b.z); s[7] = (short)f2bf(b.w);
    return s;
}
// barrier without the compiler's vmcnt(0) drain: LDS-visibility only
__device__ __forceinline__ void lds_barrier() {
    asm volatile("s_waitcnt lgkmcnt(0)\n\ts_barrier" ::: "memory");
}
// startup-path wait: spin + full acquire fence
__device__ __forceinline__ void wait_chunk(const unsigned int* flags, int k) {
    while (__hip_atomic_load(&flags[k], __ATOMIC_RELAXED,
                             __HIP_MEMORY_SCOPE_AGENT) != SENT)
        __builtin_amdgcn_s_sleep(2);
    __builtin_amdgcn_fence(__ATOMIC_ACQUIRE, "agent");
}
// hot-loop wait: spin only, NO fence (see header comment for the argument)
__device__ __forceinline__ void spin_chunk(const unsigned int* flags, int k) {
    while (__hip_atomic_load(&flags[k], __ATOMIC_RELAXED,
                             __HIP_MEMORY_SCOPE_AGENT) != SENT)
        __builtin_amdgcn_s_sleep(2);
}

// =================== fused producer/consumer kernel ==========================
__global__ __launch_bounds__(256) void lstm_fused_all(
    const int*   __restrict__ tokens,
    const float* __restrict__ emb,
    const float* __restrict__ Wih,
    const float* __restrict__ Whh,
    const float* __restrict__ bih,
    const float* __restrict__ bhh,
    unsigned short* __restrict__ xg,     // [T][64][128][4] bf16, in d_ws
    unsigned int*   __restrict__ flags,  // [NCHUNK], in d_ws after xg
    float*       __restrict__ out)       // [2][64][128] fp32
{
    __shared__ __align__(16) unsigned short albs[2][64 * XS];  // producer A-tile

    const int tid = threadIdx.x;

    if (blockIdx.x < CONS) {
        // ================= CONSUMER: one batch row ===========================
        __builtin_amdgcn_s_setprio(1);   // beat co-resident producers
        signed char (*hbuf)[128] =
            reinterpret_cast<signed char (*)[128]>(&albs[0][0]);  // [2][128]

        const int wv = tid >> 6;          // wave 0..3
        const int l  = tid & 63;
        const int kh = l & 1;             // K-half: 0 -> k<64, 1 -> k>=64
        const int c  = wv * 32 + (l >> 1);  // hidden column
        const int b  = blockIdx.x;        // batch row

        // Whh rows {g*128+c} -> i8; full-row scale, quantize own K-half
        int   wq[4][16];
        float dq[4];
#pragma unroll
        for (int g = 0; g < 4; ++g) {
            const float* wr = Whh + (size_t)(g * 128 + c) * Hh;
            float am = 0.f;
#pragma unroll 8
            for (int k = 0; k < 128; k += 4) {
                const float4 v = *reinterpret_cast<const float4*>(wr + k);
                am = fmaxf(am, fmaxf(fmaxf(fabsf(v.x), fabsf(v.y)),
                                     fmaxf(fabsf(v.z), fabsf(v.w))));
            }
            const float swm = fmaxf(am, 1e-20f);
            dq[g] = swm * (1.0f / (127.0f * 127.0f));
            const float inv = 127.0f / swm;
#pragma unroll
            for (int d = 0; d < 16; ++d) {
                const float4 v =
                    *reinterpret_cast<const float4*>(wr + kh * 64 + d * 4);
                const int b0 = (int)__builtin_rintf(v.x * inv);
                const int b1 = (int)__builtin_rintf(v.y * inv);
                const int b2 = (int)__builtin_rintf(v.z * inv);
                const int b3 = (int)__builtin_rintf(v.w * inv);
                wq[g][d] = (b0 & 0xff) | ((b1 & 0xff) << 8) |
                           ((b2 & 0xff) << 16) | ((b3 & 0xff) << 24);
            }
        }

        // h(0) = 0 in regs (buffers always written before read); own K-half
        intx4 hv[4];
#pragma unroll
        for (int j = 0; j < 4; ++j) hv[j] = (intx4){0, 0, 0, 0};

        const unsigned short* xptr = xg + (size_t)b * Gg + c * 4;
        const size_t xstride = (size_t)Bsz * Gg;

        // startup: verify chunks 0 and 1 (full acquire); load chunk 0
        wait_chunk(flags, 0);
        uintx2 xc[8];
#pragma unroll
        for (int u = 0; u < 8; ++u)
            xc[u] = *reinterpret_cast<const uintx2*>(xptr + (size_t)u * xstride);
        wait_chunk(flags, 1);

        float c_state = 0.0f;
        float h_last  = 0.0f;
        unsigned int fpre = SENT;

        for (int g = 0; g < NCHUNK; ++g) {
            int tn = g + 1;
            if (tn >= NCHUNK) tn = 0;            // dummy re-read of chunk 0
            const size_t tb = (size_t)tn * 8;
#pragma unroll
            for (int s = 0; s < 8; ++s) {
                const uintx2 xv = xc[s];          // consume slot s FIRST

                // streaming in-place prefetch of chunk g+1:
                //   substep s>=1 loads slot s-1; substep 7 also re-loads
                //   slot 7 (just consumed above). ~7-substep use distance.
                if (s >= 1)
                    xc[s - 1] = *reinterpret_cast<const uintx2*>(
                        xptr + (tb + (s - 1)) * xstride);
                if (s == 7)
                    xc[7] = *reinterpret_cast<const uintx2*>(
                        xptr + (tb + 7) * xstride);

                if (s == 2) {
                    // prefetch the distance-2 flag (hide L2 latency)
                    if (g + 2 < NCHUNK)
                        fpre = __hip_atomic_load(&flags[g + 2], __ATOMIC_RELAXED,
                                                 __HIP_MEMORY_SCOPE_AGENT);
                }
                if (s == 4) {
                    // distance-2 flag check; fence-free (see header)
                    if (g + 2 < NCHUNK && fpre != SENT) spin_chunk(flags, g + 2);
                }

                // ---- block 1: gates {2,3} = {g,o}, own K-half ----
                // 4 chains, 8-deep; first sdot4 of each chain inits with 0
                int a0, a1, b0, b1;
                {
                    const intx4 h4 = hv[0];
                    a0 = dot4i8(wq[2][0], h4[0], 0);
                    a1 = dot4i8(wq[2][1], h4[1], 0);
                    b0 = dot4i8(wq[3][0], h4[0], 0);
                    b1 = dot4i8(wq[3][1], h4[1], 0);
                    a0 = dot4i8(wq[2][2], h4[2], a0);
                    a1 = dot4i8(wq[2][3], h4[3], a1);
                    b0 = dot4i8(wq[3][2], h4[2], b0);
                    b1 = dot4i8(wq[3][3], h4[3], b1);
                }
#pragma unroll
                for (int j = 1; j < 4; ++j) {
                    const intx4 h4 = hv[j];
                    a0 = dot4i8(wq[2][j * 4 + 0], h4[0], a0);
                    a1 = dot4i8(wq[2][j * 4 + 1], h4[1], a1);
                    b0 = dot4i8(wq[3][j * 4 + 0], h4[0], b0);
                    b1 = dot4i8(wq[3][j * 4 + 1], h4[1], b1);
                    a0 = dot4i8(wq[2][j * 4 + 2], h4[2], a0);
                    a1 = dot4i8(wq[2][j * 4 + 3], h4[3], a1);
                    b0 = dot4i8(wq[3][j * 4 + 2], h4[2], b0);
                    b1 = dot4i8(wq[3][j * 4 + 3], h4[3], b1);
                }
                const int p2 = a0 + a1;            // partial sums, own K-half
                const int p3 = b0 + b1;
                // exact i32 K-merge with partner lane^1 (DPP)
                const int m2 = p2 + xor1_i(p2);
                const int m3 = p3 + xor1_i(p3);

                // g,o activations -- hidden under block 2 dot issue
                const float gv = (float)m2 * dq[2] + fi_(xv.y << 16);
                const float ov = (float)m3 * dq[3] + fi_(xv.y & 0xffff0000u);
                const float tg = tanhf_(gv);
                const float so = sigmoidf_(ov);
                const float so127 = so * 127.0f;

                // ---- block 2: gates {0,1} = {i,f}, own K-half ----
                int c0, c1, d0, d1;
                {
                    const intx4 h4 = hv[0];
                    c0 = dot4i8(wq[0][0], h4[0], 0);
                    c1 = dot4i8(wq[0][1], h4[1], 0);
                    d0 = dot4i8(wq[1][0], h4[0], 0);
                    d1 = dot4i8(wq[1][1], h4[1], 0);
                    c0 = dot4i8(wq[0][2], h4[2], c0);
                    c1 = dot4i8(wq[0][3], h4[3], c1);
                    d0 = dot4i8(wq[1][2], h4[2], d0);
                    d1 = dot4i8(wq[1][3], h4[3], d1);
                }
#pragma unroll
                for (int j = 1; j < 4; ++j) {
                    const intx4 h4 = hv[j];
                    c0 = dot4i8(wq[0][j * 4 + 0], h4[0], c0);
                    c1 = dot4i8(wq[0][j * 4 + 1], h4[1], c1);
                    d0 = dot4i8(wq[1][j * 4 + 0], h4[0], d0);
                    d1 = dot4i8(wq[1][j * 4 + 1], h4[1], d1);
                    c0 = dot4i8(wq[0][j * 4 + 2], h4[2], c0);
                    c1 = dot4i8(wq[0][j * 4 + 3], h4[3], c1);
                    d0 = dot4i8(wq[1][j * 4 + 2], h4[2], d0);
                    d1 = dot4i8(wq[1][j * 4 + 3], h4[3], d1);
                }
                const int p0 = c0 + c1;
                const int p1 = d0 + d1;
                const int m0 = p0 + xor1_i(p0);
                const int m1 = p1 + xor1_i(p1);

                // i,f activations (parallel chains) -> c update -> tanh -> h
                const float iv = (float)m0 * dq[0] + fi_(xv.x << 16);
                const float fv = (float)m1 * dq[1] + fi_(xv.x & 0xffff0000u);
                const float si = sigmoidf_(iv);
                const float sf = sigmoidf_(fv);
                c_state = __builtin_fmaf(sf, c_state, si * tg);
                const float t2 = tanhf_(c_state);
                h_last = so * t2;

                const int nxt = (s & 1) ^ 1;        // buffer parity of t+1
                if (kh == 0) {
                    // fused quant: round(so*127 * t2) via magic-add FMA (RNE)
                    const int q =
                        f_as_i(__builtin_fmaf(so127, t2, 12582912.0f));
                    hbuf[nxt][c] = (signed char)(q & 0xff);
                }
                lds_barrier();  // lgkm-only: h visible, vmem stays in flight
                // own K-half only: 4 x ds_read_b128 (half the LDS requests)
#pragma unroll
                for (int j = 0; j < 4; ++j)
                    hv[j] = *reinterpret_cast<const intx4*>(
                        &hbuf[nxt][kh * 64 + j * 16]);
            }
        }

        if (kh == 0) {
            out[b * Hh + c]            = h_last;
            out[Bsz * Hh + b * Hh + c] = c_state;
        }
    } else {
        // ================= PRODUCER: xg chunks of 8 timesteps ================
        const int pid  = blockIdx.x - CONS;
        const int wv   = tid >> 6;
        const int l    = tid & 63;
        const int quad = l >> 4;
        const int cl   = l & 15;
        const int srow = tid >> 2, sseg = tid & 3;   // staging: row, 32-col seg

        // bias for this lane's two hh columns (j = wv*2 + jj)
        float bias[2][4];
#pragma unroll
        for (int jj = 0; jj < 2; ++jj) {
            const int hhj = (wv * 2 + jj) * 16 + cl;
#pragma unroll
            for (int g = 0; g < 4; ++g)
                bias[jj][g] = bih[g * 128 + hhj] + bhh[g * 128 + hhj];
        }

        for (int chunk = pid; chunk < NCHUNK; chunk += PROD) {
            const int t0 = chunk * 8;

            {   // stage t0 into buf 0
                const int tok = tokens[srow * T_LEN + t0];
                const float* src = emb + (size_t)tok * Dd + sseg * 32;
#pragma unroll
                for (int p = 0; p < 4; ++p)
                    *reinterpret_cast<short8*>(
                        &albs[0][srow * XS + sseg * 32 + p * 8]) = ld8bf(src + p * 8);
            }
            __syncthreads();

            for (int tt = 0; tt < 8; ++tt) {
                const int cur = tt & 1, nxt = cur ^ 1;
                if (tt < 7) {   // stage next t
                    const int tok = tokens[srow * T_LEN + t0 + tt + 1];
                    const float* src = emb + (size_t)tok * Dd + sseg * 32;
#pragma unroll
                    for (int p = 0; p < 4; ++p)
                        *reinterpret_cast<short8*>(
                            &albs[nxt][srow * XS + sseg * 32 + p * 8]) =
                            ld8bf(src + p * 8);
                }

                // A-fragments for all 4 m-tiles x 4 k-chunks
                short8 af[4][4];
#pragma unroll
                for (int m = 0; m < 4; ++m)
#pragma unroll
                    for (int k = 0; k < 4; ++k)
                        af[m][k] = *reinterpret_cast<const short8*>(
                            &albs[cur][(m * 16 + cl) * XS + k * 32 + quad * 8]);

                const int t = t0 + tt;
#pragma unroll
                for (int jj = 0; jj < 2; ++jj) {
                    const int hhj = (wv * 2 + jj) * 16 + cl;
                    floatx4 acc[4][4];  // [g][m]
#pragma unroll
                    for (int g = 0; g < 4; ++g)
#pragma unroll
                        for (int m = 0; m < 4; ++m)
                            acc[g][m] = (floatx4){0.f, 0.f, 0.f, 0.f};
#pragma unroll
                    for (int g = 0; g < 4; ++g) {
                        const int n = g * 128 + hhj;
                        short8 bf[4];
#pragma unroll
                        for (int k = 0; k < 4; ++k)
                            bf[k] = ld8bf(Wih + (size_t)n * Dd + k * 32 + quad * 8);
#pragma unroll
                        for (int k = 0; k < 4; ++k)
#pragma unroll
                            for (int m = 0; m < 4; ++m)
                                acc[g][m] = MFMA16(af[m][k], bf[k], acc[g][m]);
                    }
                    // pack 4 gates per (b-row) and store 8 B
#pragma unroll
                    for (int m = 0; m < 4; ++m) {
#pragma unroll
                        for (int r = 0; r < 4; ++r) {
                            const int brow = m * 16 + quad * 4 + r;
                            union { unsigned short us[4]; uintx2 u2; } p;
#pragma unroll
                            for (int g = 0; g < 4; ++g)
                                p.us[g] = f2bf(acc[g][m][r] + bias[jj][g]);
                            *reinterpret_cast<uintx2*>(
                                xg + ((size_t)t * Bsz + brow) * Gg + hhj * 4) =
                                p.u2;
                        }
                    }
                }
                __syncthreads();  // staged buf visible; stores drained (vmcnt0)
            }

            // release: all 256 threads' stores are complete (barrier drained)
            if (tid == 0) {
                __builtin_amdgcn_fence(__ATOMIC_RELEASE, "agent");
                __hip_atomic_store(&flags[chunk], SENT, __ATOMIC_RELAXED,
                                   __HIP_MEMORY_SCOPE_AGENT);
            }
        }
    }
}

// ---------------- Fallback (R2 working kernel) if ws too small ---------------
__global__ __launch_bounds__(512, 2) void lstm_fused_fb(
    const int*   __restrict__ tokens,
    const float* __restrict__ emb,
    const float* __restrict__ Wih,
    const float* __restrict__ Whh,
    const float* __restrict__ bih,
    const float* __restrict__ bhh,
    float*       __restrict__ out)
{
    __shared__ unsigned short xbuf[2][16 * XS];
    __shared__ unsigned short hbuf2[2][16 * XS];
    __shared__ float scratch[4 * Gg];

    const int tid  = threadIdx.x;
    const int w    = tid >> 6;
    const int l    = tid & 63;
    const int quad = l >> 4;
    const int cl   = l & 15;
    const int bbase = blockIdx.x * 4;
    const int rr = tid >> 7;
    const int hh = tid & 127;

    short8 wih[4][4], whh[4][4];
    float  bias[4];
#pragma unroll
    for (int q = 0; q < 4; ++q) {
        const int n = q * 128 + w * 16 + cl;
#pragma unroll
        for (int kk = 0; kk < 4; ++kk) {
            const int k0 = kk * 32 + quad * 8;
            wih[q][kk] = ld8bf(Wih + n * Dd + k0);
            whh[q][kk] = ld8bf(Whh + n * Hh + k0);
        }
        bias[q] = bih[n] + bhh[n];
    }

    for (int i = tid; i < 16 * XS; i += 512) {
        xbuf[0][i] = 0; xbuf[1][i] = 0; hbuf2[0][i] = 0; hbuf2[1][i] = 0;
    }

    const bool gact = (tid < 128);
    const int  gr = tid >> 5;
    const int  gp = tid & 31;
    float4 gdataf = {0.f, 0.f, 0.f, 0.f};
    if (gact) {
        const int tok = tokens[(bbase + gr) * T_LEN + 0];
        gdataf = *reinterpret_cast<const float4*>(emb + (size_t)tok * Dd + gp * 4);
    }
    __syncthreads();
    if (gact) *reinterpret_cast<uintx2*>(&xbuf[0][gr * XS + gp * 4]) = f4bf(gdataf);
    if (gact) {
        const int tok = tokens[(bbase + gr) * T_LEN + 1];
        gdataf = *reinterpret_cast<const float4*>(emb + (size_t)tok * Dd + gp * 4);
    }
    __syncthreads();

    const int afrag_el = cl * XS + quad * 8;

    floatx4 acc[4];
#pragma unroll
    for (int q = 0; q < 4; ++q) acc[q] = (floatx4){bias[q], bias[q], bias[q], bias[q]};
    {
        short8 xf[4];
#pragma unroll
        for (int kk = 0; kk < 4; ++kk)
            xf[kk] = *reinterpret_cast<const short8*>(&xbuf[0][afrag_el + kk * 32]);
#pragma unroll
        for (int kk = 0; kk < 4; ++kk)
#pragma unroll
            for (int q = 0; q < 4; ++q)
                acc[q] = MFMA16(xf[kk], wih[q][kk], acc[q]);
    }

    float c_state = 0.0f, h_last = 0.0f;

    for (int t = 0; t < T_LEN; ++t) {
        const int cur = t & 1, nxt = cur ^ 1;
        short8 hf[4];
#pragma unroll
        for (int kk = 0; kk < 4; ++kk)
            hf[kk] = *reinterpret_cast<const short8*>(&hbuf2[cur][afrag_el + kk * 32]);
        if (gact && (t + 1 < T_LEN))
            *reinterpret_cast<uintx2*>(&xbuf[nxt][gr * XS + gp * 4]) = f4bf(gdataf);
        if (gact && (t + 2 < T_LEN)) {
            const int tok = tokens[(bbase + gr) * T_LEN + (t + 2)];
            gdataf = *reinterpret_cast<const float4*>(emb + (size_t)tok * Dd + gp * 4);
        }
#pragma unroll
        for (int kk = 0; kk < 4; ++kk)
#pragma unroll
            for (int q = 0; q < 4; ++q)
                acc[q] = MFMA16(hf[kk], whh[q][kk], acc[q]);
        if (quad == 0) {
#pragma unroll
            for (int q = 0; q < 4; ++q) {
                const int n = q * 128 + w * 16 + cl;
#pragma unroll
                for (int r = 0; r < 4; ++r)
                    scratch[r * Gg + n] = acc[q][r];
            }
        }
        __syncthreads();
#pragma unroll
        for (int q = 0; q < 4; ++q) acc[q] = (floatx4){bias[q], bias[q], bias[q], bias[q]};
        if (t + 1 < T_LEN) {
            short8 xf[4];
#pragma unroll
            for (int kk = 0; kk < 4; ++kk)
                xf[kk] = *reinterpret_cast<const short8*>(&xbuf[nxt][afrag_el + kk * 32]);
#pragma unroll
            for (int kk = 0; kk < 4; ++kk)
#pragma unroll
                for (int q = 0; q < 4; ++q)
                    acc[q] = MFMA16(xf[kk], wih[q][kk], acc[q]);
        }
        {
            const float iv = scratch[rr * Gg + hh];
            const float fv = scratch[rr * Gg + 128 + hh];
            const float gv = scratch[rr * Gg + 256 + hh];
            const float ov = scratch[rr * Gg + 384 + hh];
            const float si = sigmoidf_(iv);
            const float sf = sigmoidf_(fv);
            const float so = sigmoidf_(ov);
            const float tg = tanhf_(gv);
            c_state = sf * c_state + si * tg;
            h_last  = so * tanhf_(c_state);
            hbuf2[nxt][rr * XS + hh] = f2bf(h_last);
        }
        __syncthreads();
    }

    const int ob = (bbase + rr) * Hh + hh;
    out[ob]            = h_last;
    out[Bsz * Hh + ob] = c_state;
}

}  // namespace

extern "C" void kernel_launch(void* const* d_in, const int* in_sizes, int n_in,
                              void* d_out, int out_size, void* d_ws, size_t ws_size,
                              hipStream_t stream) {
    (void)in_sizes; (void)n_in; (void)out_size;
    const int*   tokens = (const int*)d_in[0];
    const float* emb    = (const float*)d_in[1];
    const float* Wih    = (const float*)d_in[2];
    const float* Whh    = (const float*)d_in[3];
    const float* bih    = (const float*)d_in[4];
    const float* bhh    = (const float*)d_in[5];

    const size_t xg_bytes = (size_t)T_LEN * Bsz * Gg * sizeof(unsigned short);  // 134 MB
    const size_t need = xg_bytes + NCHUNK * sizeof(unsigned int);
    if (ws_size >= need) {
        unsigned short* xg    = (unsigned short*)d_ws;
        unsigned int*   flags = (unsigned int*)((char*)d_ws + xg_bytes);
        lstm_fused_all<<<CONS + PROD, 256, 0, stream>>>(
            tokens, emb, Wih, Whh, bih, bhh, xg, flags, (float*)d_out);
    } else {
        lstm_fused_fb<<<16, 512, 0, stream>>>(tokens, emb, Wih, Whh, bih, bhh,
                                              (float*)d_out);
    }
}